// Round 4
// baseline (350.588 us; speedup 1.0000x reference)
//
#include <hip/hip_runtime.h>
#include <hip/hip_bf16.h>

// Self-attention fwd, B=2 H=16 S=2048 D=128, fp32 in/out, bf16 MFMA compute.
// DIAGNOSTIC/CONSERVATIVE build: no inline asm, no XOR swizzle, no tr_read.
//  - 4 waves/block, QBLK=64 (16 q/wave), KVBLK=64
//  - QK^T swapped (A=K, B=Q) -> S^T via mfma_f32_16x16x32_bf16
//  - softmax lane-local (q = lane&15), shfl_xor(16|32) across 4 k-groups
//  - V staged TRANSPOSED in LDS: V^T[128 d][68] bf16 -> PV A-frags are
//    contiguous 8B reads; PV via mfma_f32_16x16x16bf16_1k, P in registers
//  - padded LDS strides instead of swizzles (K: 132 elems, V^T: 68 elems)

typedef __attribute__((ext_vector_type(4))) float f32x4;
typedef __attribute__((ext_vector_type(8))) short s16x8;
typedef __attribute__((ext_vector_type(4))) short s16x4;

#define SDIM 2048
#define DDIM 128
#define QBLK 64
#define KBLK 64
#define NKT (SDIM / KBLK)

#define KSTRIDE 132                      // K row stride in elems (128+4 pad)
#define VSTRIDE 68                       // V^T row stride in elems (64+4 pad)
#define K_BYTES (KBLK * KSTRIDE * 2)     // 16896
#define V_BYTES (DDIM * VSTRIDE * 2)     // 17408
#define SMEM_BYTES (K_BYTES + V_BYTES)   // 34304 >= epilogue 64*129*4 = 33024

__device__ __forceinline__ short f2bf(float f) {
  union { __hip_bfloat16 b; short s; } u;
  u.b = __float2bfloat16(f);
  return u.s;
}

__global__ __launch_bounds__(256)
void attn_fwd_kernel(const float* __restrict__ qp, const float* __restrict__ kp,
                     const float* __restrict__ vp, float* __restrict__ op) {
  __shared__ alignas(16) char smem[SMEM_BYTES];
  short* klds = (short*)smem;             // K[64][KSTRIDE]
  short* vlds = (short*)(smem + K_BYTES); // V^T[128][VSTRIDE]

  const int tid  = threadIdx.x;
  const int wave = tid >> 6;
  const int lane = tid & 63;
  const int g    = lane >> 4;   // k-group 0..3
  const int c    = lane & 15;   // 16-index (q for QK output, d-row for PV A)
  const int qt   = blockIdx.x;
  const int bh   = blockIdx.y;
  const size_t base = (size_t)bh * SDIM * DDIM;
  const float scale = 0.088388347648318447f;  // 1/sqrt(128)

  // ---- Q fragments: lane (g,c) holds Q[q=c][d = dc*32 + g*8 + j], scaled ----
  s16x8 qfrag[4];
  {
    const float* qrow = qp + base + (size_t)(qt * QBLK + wave * 16 + c) * DDIM;
#pragma unroll
    for (int dc = 0; dc < 4; ++dc) {
      f32x4 x = *(const f32x4*)(qrow + dc * 32 + g * 8);
      f32x4 y = *(const f32x4*)(qrow + dc * 32 + g * 8 + 4);
      s16x8 q8;
      q8[0] = f2bf(x[0] * scale); q8[1] = f2bf(x[1] * scale);
      q8[2] = f2bf(x[2] * scale); q8[3] = f2bf(x[3] * scale);
      q8[4] = f2bf(y[0] * scale); q8[5] = f2bf(y[1] * scale);
      q8[6] = f2bf(y[2] * scale); q8[7] = f2bf(y[3] * scale);
      qfrag[dc] = q8;
    }
  }

  // O^T accumulators: o[dt][r] = O^T[d = dt*16 + 4g + r][q = c]
  f32x4 o[8];
#pragma unroll
  for (int i = 0; i < 8; ++i) o[i] = (f32x4){0.f, 0.f, 0.f, 0.f};
  float mrun = -INFINITY, lrun = 0.f;

  const f32x4* kg0 = (const f32x4*)(kp + base);
  const f32x4* vg0 = (const f32x4*)(vp + base);

  for (int kt = 0; kt < NKT; ++kt) {
    __syncthreads();
    // ---- stage K (row-major, padded) and V^T (transposed, padded) ----
    {
      const f32x4* kg = kg0 + (size_t)kt * KBLK * (DDIM / 4);
      const f32x4* vg = vg0 + (size_t)kt * KBLK * (DDIM / 4);
#pragma unroll
      for (int i = 0; i < 8; ++i) {
        const int idx = tid + i * 256;          // 0..2047 float4s
        const int r = idx >> 5, c4 = idx & 31;  // k-row, float4-col
        f32x4 a = kg[idx];
        f32x4 b = vg[idx];
        s16x4 ka;
        ka[0] = f2bf(a[0]); ka[1] = f2bf(a[1]);
        ka[2] = f2bf(a[2]); ka[3] = f2bf(a[3]);
        *(s16x4*)&klds[r * KSTRIDE + c4 * 4] = ka;   // byte 264*r + 8*c4, 8B-aligned
#pragma unroll
        for (int j = 0; j < 4; ++j)
          vlds[(c4 * 4 + j) * VSTRIDE + r] = f2bf(b[j]);
      }
    }
    __syncthreads();

    // ---- S^T = K * Q^T : st[ks][r] = S^T[k = ks*16 + 4g + r][q = c] ----
    f32x4 st[4];
#pragma unroll
    for (int ks = 0; ks < 4; ++ks) {
      f32x4 acc = (f32x4){0.f, 0.f, 0.f, 0.f};
      const short* kr = &klds[(ks * 16 + c) * KSTRIDE];
#pragma unroll
      for (int dc = 0; dc < 4; ++dc) {
        s16x4 klo = *(const s16x4*)(kr + dc * 32 + g * 8);
        s16x4 khi = *(const s16x4*)(kr + dc * 32 + g * 8 + 4);
        s16x8 kf;
        kf[0] = klo[0]; kf[1] = klo[1]; kf[2] = klo[2]; kf[3] = klo[3];
        kf[4] = khi[0]; kf[5] = khi[1]; kf[6] = khi[2]; kf[7] = khi[3];
        acc = __builtin_amdgcn_mfma_f32_16x16x32_bf16(kf, qfrag[dc], acc, 0, 0, 0);
      }
      st[ks] = acc;
    }

    // ---- online softmax over this 64-k tile (per q = c) ----
    float tmax = st[0][0];
#pragma unroll
    for (int ks = 0; ks < 4; ++ks)
#pragma unroll
      for (int r = 0; r < 4; ++r) tmax = fmaxf(tmax, st[ks][r]);
    tmax = fmaxf(tmax, __shfl_xor(tmax, 16));
    tmax = fmaxf(tmax, __shfl_xor(tmax, 32));
    const float mnew  = fmaxf(mrun, tmax);
    const float alpha = __expf(mrun - mnew);
    float tsum = 0.f;
#pragma unroll
    for (int ks = 0; ks < 4; ++ks)
#pragma unroll
      for (int r = 0; r < 4; ++r) {
        const float p = __expf(st[ks][r] - mnew);
        st[ks][r] = p;
        tsum += p;
      }
    tsum += __shfl_xor(tsum, 16);
    tsum += __shfl_xor(tsum, 32);
    lrun = lrun * alpha + tsum;
    mrun = mnew;
#pragma unroll
    for (int dt = 0; dt < 8; ++dt)
#pragma unroll
      for (int r = 0; r < 4; ++r) o[dt][r] *= alpha;

    // ---- O^T += V^T * P^T  (V^T rows contiguous in LDS; P lane-local) ----
#pragma unroll
    for (int ks = 0; ks < 4; ++ks) {
      s16x4 pf;
      pf[0] = f2bf(st[ks][0]); pf[1] = f2bf(st[ks][1]);
      pf[2] = f2bf(st[ks][2]); pf[3] = f2bf(st[ks][3]);
#pragma unroll
      for (int dt = 0; dt < 8; ++dt) {
        // A-frag: vf[j] = V^T[d = dt*16 + c][k = ks*16 + 4g + j]
        s16x4 vf = *(const s16x4*)&vlds[(dt * 16 + c) * VSTRIDE + ks * 16 + 4 * g];
        o[dt] = __builtin_amdgcn_mfma_f32_16x16x16bf16_1k(vf, pf, o[dt], 0, 0, 0);
      }
    }
  }

  // ---- epilogue: normalize, transpose O^T->O via LDS, coalesced store ----
  __syncthreads();
  const float invl = 1.f / lrun;
  float* olds = (float*)smem;
#pragma unroll
  for (int dt = 0; dt < 8; ++dt)
#pragma unroll
    for (int r = 0; r < 4; ++r)
      olds[(wave * 16 + c) * 129 + dt * 16 + g * 4 + r] = o[dt][r] * invl;
  __syncthreads();
  float* orow = op + base + (size_t)qt * QBLK * DDIM;
#pragma unroll 4
  for (int i = 0; i < 32; ++i) {
    const int idx = tid + i * 256;        // 8192 floats
    const int r = idx >> 7, d = idx & 127;
    orow[r * DDIM + d] = olds[r * 129 + d];
  }
}

extern "C" void kernel_launch(void* const* d_in, const int* in_sizes, int n_in,
                              void* d_out, int out_size, void* d_ws, size_t ws_size,
                              hipStream_t stream) {
  const float* q = (const float*)d_in[0];
  const float* k = (const float*)d_in[1];
  const float* v = (const float*)d_in[2];
  float* out = (float*)d_out;
  dim3 grid(SDIM / QBLK, 2 * 16);   // (q-tiles, B*H)
  attn_fwd_kernel<<<grid, 256, 0, stream>>>(q, k, v, out);
}

// Round 5
// 328.209 us; speedup vs baseline: 1.0682x; 1.0682x over previous
//
#include <hip/hip_runtime.h>
#include <hip/hip_bf16.h>

// Self-attention fwd, B=2 H=16 S=2048 D=128, fp32 in/out, bf16 MFMA compute.
// R5: verified R4 core + (1) vectorized register-repack V^T staging (b64
// writes, no scalar-store bank conflicts), (2) QBLK=128 (32 q/wave) so each
// LDS fragment read feeds 2 MFMAs (halves LDS bytes per FLOP).
//  - 4 waves/block, QBLK=128 (2x16 q/wave), KVBLK=64
//  - QK^T swapped (A=K, B=Q) -> S^T via mfma_f32_16x16x32_bf16
//  - softmax lane-local (q = lane&15), shfl_xor(16|32) across 4 k-groups
//  - V^T[128 d][68] bf16 in LDS; PV via mfma_f32_16x16x16bf16_1k, P in regs
//  - padded LDS strides (K: 132 elems, V^T: 68 elems), no swizzles

typedef __attribute__((ext_vector_type(4))) float f32x4;
typedef __attribute__((ext_vector_type(8))) short s16x8;
typedef __attribute__((ext_vector_type(4))) short s16x4;

#define SDIM 2048
#define DDIM 128
#define QBLK 128
#define KBLK 64
#define NKT (SDIM / KBLK)

#define KSTRIDE 132                      // K row stride in elems (128+4 pad)
#define VSTRIDE 68                       // V^T row stride in elems (64+4 pad)
#define K_BYTES (KBLK * KSTRIDE * 2)     // 16896
#define V_BYTES (DDIM * VSTRIDE * 2)     // 17408
#define SMEM_BYTES (K_BYTES + V_BYTES)   // 34304 >= epilogue 64*129*4 = 33024

__device__ __forceinline__ short f2bf(float f) {
  union { __hip_bfloat16 b; short s; } u;
  u.b = __float2bfloat16(f);
  return u.s;
}

__global__ __launch_bounds__(256)
void attn_fwd_kernel(const float* __restrict__ qp, const float* __restrict__ kp,
                     const float* __restrict__ vp, float* __restrict__ op) {
  __shared__ alignas(16) char smem[SMEM_BYTES];
  short* klds = (short*)smem;             // K[64][KSTRIDE]
  short* vlds = (short*)(smem + K_BYTES); // V^T[128][VSTRIDE]

  const int tid  = threadIdx.x;
  const int wave = tid >> 6;
  const int lane = tid & 63;
  const int g    = lane >> 4;   // k-group 0..3
  const int c    = lane & 15;   // 16-index (q for QK output, d-row for PV A)
  const int qt   = blockIdx.x;
  const int bh   = blockIdx.y;
  const size_t base = (size_t)bh * SDIM * DDIM;
  const float scale = 0.088388347648318447f;  // 1/sqrt(128)

  // ---- Q fragments: qfrag[qh]: Q[q = qt*128 + wave*32 + qh*16 + c]
  //      [d = dc*32 + g*8 + j], scaled, bf16 ----
  s16x8 qfrag[2][4];
#pragma unroll
  for (int qh = 0; qh < 2; ++qh) {
    const float* qrow =
        qp + base + (size_t)(qt * QBLK + wave * 32 + qh * 16 + c) * DDIM;
#pragma unroll
    for (int dc = 0; dc < 4; ++dc) {
      f32x4 x = *(const f32x4*)(qrow + dc * 32 + g * 8);
      f32x4 y = *(const f32x4*)(qrow + dc * 32 + g * 8 + 4);
      s16x8 q8;
      q8[0] = f2bf(x[0] * scale); q8[1] = f2bf(x[1] * scale);
      q8[2] = f2bf(x[2] * scale); q8[3] = f2bf(x[3] * scale);
      q8[4] = f2bf(y[0] * scale); q8[5] = f2bf(y[1] * scale);
      q8[6] = f2bf(y[2] * scale); q8[7] = f2bf(y[3] * scale);
      qfrag[qh][dc] = q8;
    }
  }

  // O^T accumulators: o[qh][dt][r] = O^T[d = dt*16 + 4g + r][q-sub qh, q = c]
  f32x4 o[2][8];
#pragma unroll
  for (int qh = 0; qh < 2; ++qh)
#pragma unroll
    for (int i = 0; i < 8; ++i) o[qh][i] = (f32x4){0.f, 0.f, 0.f, 0.f};
  float mrun[2] = {-INFINITY, -INFINITY};
  float lrun[2] = {0.f, 0.f};

  const f32x4* kg0 = (const f32x4*)(kp + base);
  const f32x4* vg0 = (const f32x4*)(vp + base);

  const int d4  = tid & 31;   // V staging: f32x4 col 0..31
  const int kq8 = tid >> 5;   // V staging: k-quad 0..7

  for (int kt = 0; kt < NKT; ++kt) {
    __syncthreads();
    {
      const f32x4* kg = kg0 + (size_t)kt * KBLK * (DDIM / 4);
      const f32x4* vg = vg0 + (size_t)kt * KBLK * (DDIM / 4);
      // ---- stage K row-major (b64 writes, conflict-free) ----
#pragma unroll
      for (int i = 0; i < 8; ++i) {
        const int idx = tid + i * 256;          // 0..2047 float4s
        const int r = idx >> 5, c4 = idx & 31;  // k-row, float4-col
        f32x4 a = kg[idx];
        s16x4 ka;
        ka[0] = f2bf(a[0]); ka[1] = f2bf(a[1]);
        ka[2] = f2bf(a[2]); ka[3] = f2bf(a[3]);
        *(s16x4*)&klds[r * KSTRIDE + c4 * 4] = ka;
      }
      // ---- stage V^T via register-repacked 4x4 micro-tiles (b64 writes) ----
#pragma unroll
      for (int it = 0; it < 2; ++it) {
        const int kb = 4 * (kq8 + 8 * it);      // k row base 0..60
        f32x4 a0 = vg[(kb + 0) * 32 + d4];
        f32x4 a1 = vg[(kb + 1) * 32 + d4];
        f32x4 a2 = vg[(kb + 2) * 32 + d4];
        f32x4 a3 = vg[(kb + 3) * 32 + d4];
#pragma unroll
        for (int m = 0; m < 4; ++m) {
          s16x4 w;
          w[0] = f2bf(a0[m]); w[1] = f2bf(a1[m]);
          w[2] = f2bf(a2[m]); w[3] = f2bf(a3[m]);
          *(s16x4*)&vlds[(4 * d4 + m) * VSTRIDE + kb] = w;
        }
      }
    }
    __syncthreads();

    // ---- S^T = K * Q^T : st[qh][ks][r] = S^T[k = ks*16+4g+r][q-sub qh] ----
    f32x4 st[2][4];
#pragma unroll
    for (int ks = 0; ks < 4; ++ks) {
      const short* kr = &klds[(ks * 16 + c) * KSTRIDE];
      s16x8 kf[4];
#pragma unroll
      for (int dc = 0; dc < 4; ++dc) {
        s16x4 klo = *(const s16x4*)(kr + dc * 32 + g * 8);
        s16x4 khi = *(const s16x4*)(kr + dc * 32 + g * 8 + 4);
        s16x8 kk;
        kk[0] = klo[0]; kk[1] = klo[1]; kk[2] = klo[2]; kk[3] = klo[3];
        kk[4] = khi[0]; kk[5] = khi[1]; kk[6] = khi[2]; kk[7] = khi[3];
        kf[dc] = kk;
      }
#pragma unroll
      for (int qh = 0; qh < 2; ++qh) {
        f32x4 acc = (f32x4){0.f, 0.f, 0.f, 0.f};
#pragma unroll
        for (int dc = 0; dc < 4; ++dc)
          acc = __builtin_amdgcn_mfma_f32_16x16x32_bf16(kf[dc], qfrag[qh][dc],
                                                        acc, 0, 0, 0);
        st[qh][ks] = acc;
      }
    }

    // ---- online softmax per q-sub (q = c lane-local) ----
    float alpha[2];
#pragma unroll
    for (int qh = 0; qh < 2; ++qh) {
      float tmax = st[qh][0][0];
#pragma unroll
      for (int ks = 0; ks < 4; ++ks)
#pragma unroll
        for (int r = 0; r < 4; ++r) tmax = fmaxf(tmax, st[qh][ks][r]);
      tmax = fmaxf(tmax, __shfl_xor(tmax, 16));
      tmax = fmaxf(tmax, __shfl_xor(tmax, 32));
      const float mnew = fmaxf(mrun[qh], tmax);
      alpha[qh] = __expf(mrun[qh] - mnew);
      float tsum = 0.f;
#pragma unroll
      for (int ks = 0; ks < 4; ++ks)
#pragma unroll
        for (int r = 0; r < 4; ++r) {
          const float p = __expf(st[qh][ks][r] - mnew);
          st[qh][ks][r] = p;
          tsum += p;
        }
      tsum += __shfl_xor(tsum, 16);
      tsum += __shfl_xor(tsum, 32);
      lrun[qh] = lrun[qh] * alpha[qh] + tsum;
      mrun[qh] = mnew;
#pragma unroll
      for (int dt = 0; dt < 8; ++dt)
#pragma unroll
        for (int r = 0; r < 4; ++r) o[qh][dt][r] *= alpha[qh];
    }

    // ---- O^T += V^T * P^T  (V^T rows contiguous; each vf feeds 2 MFMAs) ----
#pragma unroll
    for (int ks = 0; ks < 4; ++ks) {
      s16x4 pf[2];
#pragma unroll
      for (int qh = 0; qh < 2; ++qh) {
        s16x4 p4;
        p4[0] = f2bf(st[qh][ks][0]); p4[1] = f2bf(st[qh][ks][1]);
        p4[2] = f2bf(st[qh][ks][2]); p4[3] = f2bf(st[qh][ks][3]);
        pf[qh] = p4;
      }
#pragma unroll
      for (int dt = 0; dt < 8; ++dt) {
        // vf[j] = V^T[d = dt*16 + c][k = ks*16 + 4g + j]
        s16x4 vf = *(const s16x4*)&vlds[(dt * 16 + c) * VSTRIDE + ks * 16 + 4 * g];
        o[0][dt] = __builtin_amdgcn_mfma_f32_16x16x16bf16_1k(vf, pf[0], o[0][dt], 0, 0, 0);
        o[1][dt] = __builtin_amdgcn_mfma_f32_16x16x16bf16_1k(vf, pf[1], o[1][dt], 0, 0, 0);
      }
    }
  }

  // ---- epilogue: normalize, transpose O^T->O via LDS (two passes) ----
  float* olds = (float*)smem;
  float* orow = op + base + (size_t)qt * QBLK * DDIM;
#pragma unroll
  for (int qh = 0; qh < 2; ++qh) {
    __syncthreads();
    const float invl = 1.f / lrun[qh];
#pragma unroll
    for (int dt = 0; dt < 8; ++dt)
#pragma unroll
      for (int r = 0; r < 4; ++r)
        olds[(wave * 16 + c) * 129 + dt * 16 + g * 4 + r] = o[qh][dt][r] * invl;
    __syncthreads();
#pragma unroll 4
    for (int i = 0; i < 32; ++i) {
      const int idx = tid + i * 256;        // 8192 floats
      const int lr = idx >> 7, d = idx & 127;
      const int q = (lr >> 4) * 32 + qh * 16 + (lr & 15);  // wave*32+qh*16+row
      orow[q * DDIM + d] = olds[lr * 129 + d];
    }
  }
}

extern "C" void kernel_launch(void* const* d_in, const int* in_sizes, int n_in,
                              void* d_out, int out_size, void* d_ws, size_t ws_size,
                              hipStream_t stream) {
  const float* q = (const float*)d_in[0];
  const float* k = (const float*)d_in[1];
  const float* v = (const float*)d_in[2];
  float* out = (float*)d_out;
  dim3 grid(SDIM / QBLK, 2 * 16);   // (q-tiles, B*H)
  attn_fwd_kernel<<<grid, 256, 0, stream>>>(q, k, v, out);
}

// Round 6
// 282.999 us; speedup vs baseline: 1.2388x; 1.1598x over previous
//
#include <hip/hip_runtime.h>
#include <hip/hip_bf16.h>

// Self-attention fwd, B=2 H=16 S=2048 D=128, fp32 in/out, bf16 MFMA compute.
// R6: R5 core + 2-phase pipeline (T14): prefetch tile t+1 to regs BEFORE
// compute(t), convert+write to alternate LDS buffer AFTER, single barrier/iter
// (double-buffered LDS). All LDS frag reads are b128 at the bank floor:
//  - K: 64 rows x 256B, 16B-unit XOR swizzle u^=(r&7).
//    write: pair p (16B) of row r at byte (r<<8) + 16*(p^(r&7))
//    read : lane(g,c) ks,dc: row r=ks*16+c, unit 4dc+g -> byte
//           (r<<8) + 16*((4dc+g)^(c&7))   [(r&7)=(c&7)]
//  - V^T: 128 rows(d) x 128B, k-permuted pos = (k>>2&3)*16 + (k>>4)*4 + (k&3),
//    32B-unit XOR swizzle u^=((d>>2)&3). One 32B read per (dt) covers all 4 ks.
//  - QK^T swapped (A=K,B=Q) -> S^T; softmax lane-local (q=lane&15)
//  - PV via mfma_f32_16x16x16bf16_1k, P in regs, 2 q-subtiles/wave (QBLK=128)

typedef __attribute__((ext_vector_type(4))) float f32x4;
typedef __attribute__((ext_vector_type(8))) short s16x8;
typedef __attribute__((ext_vector_type(4))) short s16x4;

#define SDIM 2048
#define DDIM 128
#define QBLK 128
#define KBLK 64
#define NKT (SDIM / KBLK)

#define KT_BYTES 16384                  // 64 x 256 B (swizzled)
#define VT_BYTES 16384                  // 128 x 128 B (swizzled)
#define BUF_BYTES (KT_BYTES + VT_BYTES) // 32768
#define SMEM_BYTES (2 * BUF_BYTES)      // 65536; epilogue needs 33024

__device__ __forceinline__ short f2bf(float f) {
  union { __hip_bfloat16 b; short s; } u;
  u.b = __float2bfloat16(f);
  return u.s;
}

__global__ __launch_bounds__(256)
void attn_fwd_kernel(const float* __restrict__ qp, const float* __restrict__ kp,
                     const float* __restrict__ vp, float* __restrict__ op) {
  __shared__ alignas(128) char smem[SMEM_BYTES];
  const int tid  = threadIdx.x;
  const int wave = tid >> 6;
  const int lane = tid & 63;
  const int g    = lane >> 4;   // k-group 0..3
  const int c    = lane & 15;   // q (QK out) / d-row (PV A)
  const int qt   = blockIdx.x;
  const int bh   = blockIdx.y;
  const size_t base = (size_t)bh * SDIM * DDIM;
  const float scale = 0.088388347648318447f;  // 1/sqrt(128)

  // staging thread mapping
  const int d4  = tid & 31;   // V: f32x4 column 0..31
  const int kq8 = tid >> 5;   // V: k-quad 0..7

  // ---- Q fragments: qfrag[qh][dc]: Q[q = qt*128+wave*32+qh*16+c]
  //      [d = dc*32 + g*8 + j], scaled, bf16 ----
  s16x8 qfrag[2][4];
#pragma unroll
  for (int qh = 0; qh < 2; ++qh) {
    const float* qrow =
        qp + base + (size_t)(qt * QBLK + wave * 32 + qh * 16 + c) * DDIM;
#pragma unroll
    for (int dc = 0; dc < 4; ++dc) {
      f32x4 x = *(const f32x4*)(qrow + dc * 32 + g * 8);
      f32x4 y = *(const f32x4*)(qrow + dc * 32 + g * 8 + 4);
      s16x8 q8;
      q8[0] = f2bf(x[0] * scale); q8[1] = f2bf(x[1] * scale);
      q8[2] = f2bf(x[2] * scale); q8[3] = f2bf(x[3] * scale);
      q8[4] = f2bf(y[0] * scale); q8[5] = f2bf(y[1] * scale);
      q8[6] = f2bf(y[2] * scale); q8[7] = f2bf(y[3] * scale);
      qfrag[qh][dc] = q8;
    }
  }

  f32x4 o[2][8];
#pragma unroll
  for (int qh = 0; qh < 2; ++qh)
#pragma unroll
    for (int i = 0; i < 8; ++i) o[qh][i] = (f32x4){0.f, 0.f, 0.f, 0.f};
  float mrun[2] = {-INFINITY, -INFINITY};
  float lrun[2] = {0.f, 0.f};

  const f32x4* kg0 = (const f32x4*)(kp + base);
  const f32x4* vg0 = (const f32x4*)(vp + base);

  f32x4 kpre[8], vpre[8];

  auto LOADR = [&](int kt2) {
    const f32x4* kg = kg0 + (size_t)kt2 * KBLK * (DDIM / 4);
    const f32x4* vg = vg0 + (size_t)kt2 * KBLK * (DDIM / 4);
#pragma unroll
    for (int pi = 0; pi < 4; ++pi) {
      const int pair = tid + pi * 256;          // 0..1023 (16B-pairs)
      const int r = pair >> 4, p = pair & 15;
      kpre[2 * pi]     = kg[r * 32 + 2 * p];
      kpre[2 * pi + 1] = kg[r * 32 + 2 * p + 1];
    }
#pragma unroll
    for (int it = 0; it < 2; ++it) {
      const int kb = 4 * (kq8 + 8 * it);
#pragma unroll
      for (int j = 0; j < 4; ++j)
        vpre[4 * it + j] = vg[(kb + j) * 32 + d4];
    }
  };

  auto CONVW = [&](char* kdst, char* vdst) {
    // K: b128 stores, swizzled
#pragma unroll
    for (int pi = 0; pi < 4; ++pi) {
      const int pair = tid + pi * 256;
      const int r = pair >> 4, p = pair & 15;
      f32x4 a = kpre[2 * pi], b2 = kpre[2 * pi + 1];
      s16x8 w;
      w[0] = f2bf(a[0]);  w[1] = f2bf(a[1]);
      w[2] = f2bf(a[2]);  w[3] = f2bf(a[3]);
      w[4] = f2bf(b2[0]); w[5] = f2bf(b2[1]);
      w[6] = f2bf(b2[2]); w[7] = f2bf(b2[3]);
      *(s16x8*)(kdst + (r << 8) + 16 * (p ^ (r & 7))) = w;
    }
    // V^T: register-repacked 4x4 micro-tiles, k-permuted + swizzled
#pragma unroll
    for (int it = 0; it < 2; ++it) {
      const int t = kq8 + 8 * it;               // k-quad 0..15
#pragma unroll
      for (int m = 0; m < 4; ++m) {
        const int d = 4 * d4 + m;
        s16x4 w;
        w[0] = f2bf(vpre[4 * it + 0][m]); w[1] = f2bf(vpre[4 * it + 1][m]);
        w[2] = f2bf(vpre[4 * it + 2][m]); w[3] = f2bf(vpre[4 * it + 3][m]);
        *(s16x4*)(vdst + (d << 7) + 32 * ((t & 3) ^ (d4 & 3)) + 8 * (t >> 2)) = w;
      }
    }
  };

  // ---- prologue: stage tile 0 ----
  LOADR(0);
  CONVW(smem, smem + KT_BYTES);
  __syncthreads();
  int cur = 0;

  for (int kt = 0; kt < NKT; ++kt) {
    // issue prefetch for next tile (clamped on last iter; harmless redo)
    const int ktn = (kt + 1 < NKT) ? kt + 1 : kt;
    LOADR(ktn);

    char* kbase = smem + cur * BUF_BYTES;
    char* vbase = kbase + KT_BYTES;

    // ---- S^T = K * Q^T : st[qh][ks][r] = S^T[k=ks*16+4g+r][q-sub qh] ----
    f32x4 st[2][4];
    const int rx = c & 7;
#pragma unroll
    for (int ks = 0; ks < 4; ++ks) {
      const char* kb_ = kbase + ((ks * 16 + c) << 8);
      s16x8 kf[4];
#pragma unroll
      for (int dc = 0; dc < 4; ++dc)
        kf[dc] = *(const s16x8*)(kb_ + 16 * ((4 * dc + g) ^ rx));
#pragma unroll
      for (int qh = 0; qh < 2; ++qh) {
        f32x4 acc = (f32x4){0.f, 0.f, 0.f, 0.f};
#pragma unroll
        for (int dc = 0; dc < 4; ++dc)
          acc = __builtin_amdgcn_mfma_f32_16x16x32_bf16(kf[dc], qfrag[qh][dc],
                                                        acc, 0, 0, 0);
        st[qh][ks] = acc;
      }
    }

    // ---- online softmax per q-sub (q = c lane-local) ----
#pragma unroll
    for (int qh = 0; qh < 2; ++qh) {
      float tmax = st[qh][0][0];
#pragma unroll
      for (int ks = 0; ks < 4; ++ks)
#pragma unroll
        for (int r = 0; r < 4; ++r) tmax = fmaxf(tmax, st[qh][ks][r]);
      tmax = fmaxf(tmax, __shfl_xor(tmax, 16));
      tmax = fmaxf(tmax, __shfl_xor(tmax, 32));
      const float mnew = fmaxf(mrun[qh], tmax);
      const float alpha = __expf(mrun[qh] - mnew);
      float tsum = 0.f;
#pragma unroll
      for (int ks = 0; ks < 4; ++ks)
#pragma unroll
        for (int r = 0; r < 4; ++r) {
          const float p = __expf(st[qh][ks][r] - mnew);
          st[qh][ks][r] = p;
          tsum += p;
        }
      tsum += __shfl_xor(tsum, 16);
      tsum += __shfl_xor(tsum, 32);
      lrun[qh] = lrun[qh] * alpha + tsum;
      mrun[qh] = mnew;
#pragma unroll
      for (int dt = 0; dt < 8; ++dt)
#pragma unroll
        for (int r = 0; r < 4; ++r) o[qh][dt][r] *= alpha;
    }

    // ---- O^T += V^T * P^T ----
    s16x4 pf[4][2];
#pragma unroll
    for (int ks = 0; ks < 4; ++ks)
#pragma unroll
      for (int qh = 0; qh < 2; ++qh) {
        s16x4 p4;
        p4[0] = f2bf(st[qh][ks][0]); p4[1] = f2bf(st[qh][ks][1]);
        p4[2] = f2bf(st[qh][ks][2]); p4[3] = f2bf(st[qh][ks][3]);
        pf[ks][qh] = p4;
      }
    const int vsw = (c >> 2) & 3;
#pragma unroll
    for (int dt = 0; dt < 8; ++dt) {
      const int d = dt * 16 + c;
      const char* vb = vbase + (d << 7) + 32 * (g ^ vsw);
      s16x8 v8a = *(const s16x8*)(vb);        // ks=0 (elems 0-3), ks=1 (4-7)
      s16x8 v8b = *(const s16x8*)(vb + 16);   // ks=2, ks=3
      s16x4 vf0 = __builtin_shufflevector(v8a, v8a, 0, 1, 2, 3);
      s16x4 vf1 = __builtin_shufflevector(v8a, v8a, 4, 5, 6, 7);
      s16x4 vf2 = __builtin_shufflevector(v8b, v8b, 0, 1, 2, 3);
      s16x4 vf3 = __builtin_shufflevector(v8b, v8b, 4, 5, 6, 7);
      o[0][dt] = __builtin_amdgcn_mfma_f32_16x16x16bf16_1k(vf0, pf[0][0], o[0][dt], 0, 0, 0);
      o[1][dt] = __builtin_amdgcn_mfma_f32_16x16x16bf16_1k(vf0, pf[0][1], o[1][dt], 0, 0, 0);
      o[0][dt] = __builtin_amdgcn_mfma_f32_16x16x16bf16_1k(vf1, pf[1][0], o[0][dt], 0, 0, 0);
      o[1][dt] = __builtin_amdgcn_mfma_f32_16x16x16bf16_1k(vf1, pf[1][1], o[1][dt], 0, 0, 0);
      o[0][dt] = __builtin_amdgcn_mfma_f32_16x16x16bf16_1k(vf2, pf[2][0], o[0][dt], 0, 0, 0);
      o[1][dt] = __builtin_amdgcn_mfma_f32_16x16x16bf16_1k(vf2, pf[2][1], o[1][dt], 0, 0, 0);
      o[0][dt] = __builtin_amdgcn_mfma_f32_16x16x16bf16_1k(vf3, pf[3][0], o[0][dt], 0, 0, 0);
      o[1][dt] = __builtin_amdgcn_mfma_f32_16x16x16bf16_1k(vf3, pf[3][1], o[1][dt], 0, 0, 0);
    }

    // ---- write prefetched tile to alternate buffer; single barrier ----
    CONVW(smem + (cur ^ 1) * BUF_BYTES, smem + (cur ^ 1) * BUF_BYTES + KT_BYTES);
    __syncthreads();
    cur ^= 1;
  }

  // ---- epilogue: normalize, transpose O^T->O via LDS (two passes) ----
  float* olds = (float*)smem;
  float* orow = op + base + (size_t)qt * QBLK * DDIM;
#pragma unroll
  for (int qh = 0; qh < 2; ++qh) {
    __syncthreads();
    const float invl = 1.f / lrun[qh];
#pragma unroll
    for (int dt = 0; dt < 8; ++dt)
#pragma unroll
      for (int r = 0; r < 4; ++r)
        olds[(wave * 16 + c) * 129 + dt * 16 + g * 4 + r] = o[qh][dt][r] * invl;
    __syncthreads();
#pragma unroll 4
    for (int i = 0; i < 32; ++i) {
      const int idx = tid + i * 256;        // 8192 floats
      const int lr = idx >> 7, d = idx & 127;
      const int q = (lr >> 4) * 32 + qh * 16 + (lr & 15);
      orow[q * DDIM + d] = olds[lr * 129 + d];
    }
  }
}

extern "C" void kernel_launch(void* const* d_in, const int* in_sizes, int n_in,
                              void* d_out, int out_size, void* d_ws, size_t ws_size,
                              hipStream_t stream) {
  const float* q = (const float*)d_in[0];
  const float* k = (const float*)d_in[1];
  const float* v = (const float*)d_in[2];
  float* out = (float*)d_out;
  dim3 grid(SDIM / QBLK, 2 * 16);   // (q-tiles, B*H)
  attn_fwd_kernel<<<grid, 256, 0, stream>>>(q, k, v, out);
}